// Round 8
// baseline (939.219 us; speedup 1.0000x reference)
//
#include <hip/hip_runtime.h>
#include <stdint.h>

// Link predictor: score[e] = MLP([src,dst,src*dst,|src-dst|]) over 500K edges.
// Round 11: persistent-block software pipeline. Evidence: r10 showed VGPR=56
// (compiler sinks gather loads; batch restructure = identical codegen), dur
// 159us = r7 (bank conflicts were fully hidden), all utils <45% -> the kernel
// is a latency-chain: ~50K cycles/block for ~2K cycles of compute.
// Design:
//  - grid = 768 persistent blocks (3/CU), each strides over ~10 tiles.
//  - tile t+1's 128 gather rows are prefetched into regs (sv/dv, 64 VGPR)
//    during tile t's GEMM2..final phases. Exposed gathers: 7813 -> 768.
//  - vmcnt is IN-ORDER: prefetch issues AFTER the last global load of the
//    body (stage2 frags, preloaded to regs); b1/b2/w3/b3 moved to a one-time
//    LDS stash so no later-phase global loads force-drain the prefetch.
//  - __syncthreads full-drains vmcnt (m97 barrier-drain), so the 3 barriers
//    between issue and consumption are raw s_barrier + lgkmcnt(0) (m201
//    pattern). LDS hazards at those 3 points need only lgkm ordering:
//    sync6 h1-reads done before h2-writes; sync7 h2-writes before h2-reads;
//    sync8 h2-reads before next-tile convert-writes.
//  - __launch_bounds__(256,3): peak live ~132 VGPR (sv/dv 64 + b2frag 16 +
//    acc2 16 + misc), cap ~168. Occupancy 12 waves/CU by design.
// Keeps: derive-once GEMM1 split (r7, -16us), zero-conflict derive (r8).
// d_ws: stage1 = W1 bf16 B-frag layout (65536 shorts), stage2 = W2 (8192 shorts).

typedef __bf16 bf16x8 __attribute__((ext_vector_type(8)));
typedef __bf16 bf16x4 __attribute__((ext_vector_type(4)));
typedef float  f32x4  __attribute__((ext_vector_type(4)));

__device__ __forceinline__ short f2bf(float f) {
    union { float f; uint32_t u; } v; v.f = f;
    uint32_t u = v.u;
    uint32_t r = (u + 0x7fffu + ((u >> 16) & 1u)) >> 16;   // RNE
    return (short)r;
}

// ---------------- prep: W1/W2 fp32 -> bf16 B-fragment layout ----------------
// stage1[((ntile*16+kstep)*64+lane)*8+j] = bf16(W1[k*128+n]),
//   k = kstep*32 + (lane>>4)*8 + j, n = ntile*16 + (lane&15).
// kstep 0..3 = s rows of W1, 4..7 = d, 8..11 = it, 12..15 = df.
__global__ void prep_kernel(const float* __restrict__ W1, const float* __restrict__ W2,
                            short* __restrict__ stage1, short* __restrict__ stage2) {
    int idx = blockIdx.x * 256 + threadIdx.x;
    if (idx < 65536) {
        int k = idx >> 7, n = idx & 127;
        float v = W1[idx];
        int ntile = n >> 4, ln = n & 15;
        int kstep = k >> 5, kr = k & 31;
        int lane = (kr >> 3) * 16 + ln;
        int j = kr & 7;
        stage1[(((ntile * 16 + kstep) * 64 + lane) << 3) + j] = f2bf(v);
    } else if (idx < 65536 + 8192) {
        int i2 = idx - 65536;
        int k = i2 >> 6, n = i2 & 63;
        float v = W2[i2];
        int ntile = n >> 4, ln = n & 15;
        int kstep = k >> 5, kr = k & 31;
        int lane = (kr >> 3) * 16 + ln;
        int j = kr & 7;
        stage2[(((ntile * 4 + kstep) * 64 + lane) << 3) + j] = f2bf(v);
    }
}

// ---------------- main ----------------
// 64 edges/tile, 256 threads (4 waves), 32KB LDS + 1KB bias stash.
// LDS: s-tile [64 x 128]bf16 at 0 (stride 256B), d-tile at 16384.
//   16B chunk cc = k>>3 stored at physical chunk cc ^ (m&15) (XOR swizzle).
// After GEMM1a: s-tile overwritten in place with it, d-tile with df.
// After GEMM1b: [0,16384) reused for h1 bf16 [64x128] (same swizzle).
// After GEMM2: [0,17408) holds h2 fp32 [64 x 68] (stride 272B).
// sbias: b1[0..128) b2[128..192) w3[192..256) b3 at [256].
__launch_bounds__(256, 3)
__global__ void link_kernel(const float* __restrict__ z,
                            const int*   __restrict__ ei,
                            const float* __restrict__ b1,
                            const float* __restrict__ b2,
                            const float* __restrict__ w3,
                            const float* __restrict__ b3,
                            const short* __restrict__ stage1,
                            const short* __restrict__ stage2,
                            float* __restrict__ out,
                            int E, int ntiles) {
    __shared__ __align__(16) char smem[32768];
    __shared__ __align__(16) float sbias[260];

    const int tid  = threadIdx.x;
    const int lane = tid & 63;
    const int wave = tid >> 6;
    const int ln15 = lane & 15;
    const int quad = lane >> 4;
    const int G    = gridDim.x;

    // ---- one-time bias stash (visible after first __syncthreads) ----
    if (tid < 128)      sbias[tid] = b1[tid];
    else if (tid < 192) sbias[tid] = b2[tid - 128];
    else                sbias[tid] = w3[tid - 192];
    if (tid == 0) sbias[256] = b3[0];

    const int c    = tid & 31;
    const int mrow = tid >> 5;
    const int cc   = c >> 1;
    const int half = c & 1;

    int si[8], di[8];
    f32x4 sv[8], dv[8];

    int T = blockIdx.x;
    // ---- prologue: indices + row-load issue for tile T ----
    {
        int e0 = T * 64;
        #pragma unroll
        for (int i = 0; i < 8; ++i) {
            int eg = e0 + mrow + i * 8;
            int egc = eg < E ? eg : (E - 1);
            si[i] = ei[egc];
            di[i] = ei[E + egc];
        }
        #pragma unroll
        for (int i = 0; i < 8; ++i) {
            sv[i] = *(const f32x4*)(z + (size_t)si[i] * 128 + c * 4);
            dv[i] = *(const f32x4*)(z + (size_t)di[i] * 128 + c * 4);
        }
    }

    for (; T < ntiles; T += G) {
        const int e0 = T * 64;
        const bool hasNext = (T + G) < ntiles;   // block-uniform

        // ---- converts: sv/dv (prefetched) -> LDS bf16 tiles, swizzled ----
        #pragma unroll
        for (int i = 0; i < 8; ++i) {
            int m = mrow + i * 8;
            int addr = m * 256 + ((cc ^ (m & 15)) << 4) + half * 8;
            bf16x4 ps, pd;
            #pragma unroll
            for (int j = 0; j < 4; ++j) { ps[j] = (__bf16)sv[i][j]; pd[j] = (__bf16)dv[i][j]; }
            *(bf16x4*)(smem + addr)         = ps;
            *(bf16x4*)(smem + 16384 + addr) = pd;
        }
        __syncthreads();   // sync1 (also publishes sbias on first iteration)

        // ---- next-tile index loads (L2-hot; latency covered by GEMM1a) ----
        if (hasNext) {
            int en0 = (T + G) * 64;
            #pragma unroll
            for (int i = 0; i < 8; ++i) {
                int eg = en0 + mrow + i * 8;
                int egc = eg < E ? eg : (E - 1);
                si[i] = ei[egc];
                di[i] = ei[E + egc];
            }
        }

        // ---- GEMM1a: acc += s@W1s + d@W1d. Wave owns n-tiles wave*2,+1 ----
        f32x4 acc[4][2];
        #pragma unroll
        for (int mt = 0; mt < 4; ++mt)
            #pragma unroll
            for (int nt = 0; nt < 2; ++nt)
                acc[mt][nt] = (f32x4){0.f, 0.f, 0.f, 0.f};

        #pragma unroll
        for (int ks4 = 0; ks4 < 4; ++ks4) {
            bf16x8 Bs[2], Bd[2];
            #pragma unroll
            for (int nt = 0; nt < 2; ++nt) {
                int ntile = wave * 2 + nt;
                Bs[nt] = *(const bf16x8*)(stage1 + (((ntile * 16 + 0 + ks4) * 64 + lane) << 3));
                Bd[nt] = *(const bf16x8*)(stage1 + (((ntile * 16 + 4 + ks4) * 64 + lane) << 3));
            }
            #pragma unroll
            for (int mt = 0; mt < 4; ++mt) {
                int m = mt * 16 + ln15;
                int off = m * 256 + (((ks4 * 4 + quad) ^ (m & 15)) << 4);
                bf16x8 sf = *(const bf16x8*)(smem + off);
                bf16x8 df = *(const bf16x8*)(smem + 16384 + off);
                #pragma unroll
                for (int nt = 0; nt < 2; ++nt) {
                    acc[mt][nt] = __builtin_amdgcn_mfma_f32_16x16x32_bf16(sf, Bs[nt], acc[mt][nt], 0, 0, 0);
                    acc[mt][nt] = __builtin_amdgcn_mfma_f32_16x16x32_bf16(df, Bd[nt], acc[mt][nt], 0, 0, 0);
                }
            }
        }
        __syncthreads();   // sync2

        // ---- derive ONCE: it -> s-region, df -> d-region (zero-conflict) ----
        {
            int mder = wave * 16 + ln15;    // mder & 15 == ln15
            #pragma unroll
            for (int ks4 = 0; ks4 < 4; ++ks4) {
                int addr = mder * 256 + (((ks4 * 4 + quad) ^ ln15) << 4);
                bf16x8 s = *(const bf16x8*)(smem + addr);
                bf16x8 d = *(const bf16x8*)(smem + 16384 + addr);
                bf16x8 it, dd;
                #pragma unroll
                for (int j = 0; j < 8; ++j) {
                    float fs = (float)s[j], fd = (float)d[j];
                    it[j] = (__bf16)(fs * fd);
                    dd[j] = (__bf16)__builtin_fabsf(fs - fd);
                }
                *(bf16x8*)(smem + addr)         = it;
                *(bf16x8*)(smem + 16384 + addr) = dd;
            }
        }
        __syncthreads();   // sync3

        // ---- GEMM1b: acc += it@W1it + df@W1df ----
        #pragma unroll
        for (int ks4 = 0; ks4 < 4; ++ks4) {
            bf16x8 Bi[2], Bf[2];
            #pragma unroll
            for (int nt = 0; nt < 2; ++nt) {
                int ntile = wave * 2 + nt;
                Bi[nt] = *(const bf16x8*)(stage1 + (((ntile * 16 +  8 + ks4) * 64 + lane) << 3));
                Bf[nt] = *(const bf16x8*)(stage1 + (((ntile * 16 + 12 + ks4) * 64 + lane) << 3));
            }
            #pragma unroll
            for (int mt = 0; mt < 4; ++mt) {
                int m = mt * 16 + ln15;
                int off = m * 256 + (((ks4 * 4 + quad) ^ (m & 15)) << 4);
                bf16x8 itf = *(const bf16x8*)(smem + off);
                bf16x8 ddf = *(const bf16x8*)(smem + 16384 + off);
                #pragma unroll
                for (int nt = 0; nt < 2; ++nt) {
                    acc[mt][nt] = __builtin_amdgcn_mfma_f32_16x16x32_bf16(itf, Bi[nt], acc[mt][nt], 0, 0, 0);
                    acc[mt][nt] = __builtin_amdgcn_mfma_f32_16x16x32_bf16(ddf, Bf[nt], acc[mt][nt], 0, 0, 0);
                }
            }
        }
        __syncthreads();   // sync4

        // ---- epilogue 1: h1 = relu(acc + b1) -> LDS bf16, swizzled ----
        #pragma unroll
        for (int nt = 0; nt < 2; ++nt) {
            int n = (wave * 2 + nt) * 16 + ln15;
            float bias = sbias[n];
            #pragma unroll
            for (int mt = 0; mt < 4; ++mt) {
                #pragma unroll
                for (int r = 0; r < 4; ++r) {
                    int row = mt * 16 + quad * 4 + r;
                    float h = acc[mt][nt][r] + bias;
                    h = h > 0.f ? h : 0.f;
                    int addr = row * 256 + (((n >> 3) ^ (row & 15)) << 4) + (n & 7) * 2;
                    *(short*)(smem + addr) = f2bf(h);
                }
            }
        }
        __syncthreads();   // sync5

        // ---- GEMM2: h1 @ W2; B-frags preloaded, then PREFETCH ISSUE ----
        f32x4 acc2[4];
        #pragma unroll
        for (int mt = 0; mt < 4; ++mt) acc2[mt] = (f32x4){0.f, 0.f, 0.f, 0.f};

        bf16x8 b2frag[4];
        #pragma unroll
        for (int ks = 0; ks < 4; ++ks)
            b2frag[ks] = *(const bf16x8*)(stage2 + (((wave * 4 + ks) * 64 + lane) << 3));

        // prefetch next tile's rows: issued after the body's LAST global
        // loads (b2frag), so no later vmcnt wait force-drains them.
        if (hasNext) {
            #pragma unroll
            for (int i = 0; i < 8; ++i) {
                sv[i] = *(const f32x4*)(z + (size_t)si[i] * 128 + c * 4);
                dv[i] = *(const f32x4*)(z + (size_t)di[i] * 128 + c * 4);
            }
        }

        #pragma unroll
        for (int ks = 0; ks < 4; ++ks) {
            #pragma unroll
            for (int mt = 0; mt < 4; ++mt) {
                int m = mt * 16 + ln15;
                int ccr = ks * 4 + quad;
                bf16x8 a = *(const bf16x8*)(smem + m * 256 + ((ccr ^ (m & 15)) << 4));
                acc2[mt] = __builtin_amdgcn_mfma_f32_16x16x32_bf16(a, b2frag[ks], acc2[mt], 0, 0, 0);
            }
        }
        // sync6 (RAW: lgkm only — prefetch vmcnt survives). Hazard: all waves'
        // h1 ds_reads complete before epi2 overwrites [0,17408).
        asm volatile("s_waitcnt lgkmcnt(0)" ::: "memory");
        __builtin_amdgcn_s_barrier();

        // ---- epilogue 2: h2 = relu(acc2 + b2) -> LDS fp32 [64 x 68] ----
        {
            int n2 = wave * 16 + ln15;
            float bias = sbias[128 + n2];
            #pragma unroll
            for (int mt = 0; mt < 4; ++mt) {
                #pragma unroll
                for (int r = 0; r < 4; ++r) {
                    int row = mt * 16 + quad * 4 + r;
                    float h = acc2[mt][r] + bias;
                    h = h > 0.f ? h : 0.f;
                    *(float*)(smem + row * 272 + n2 * 4) = h;
                }
            }
        }
        // sync7 (RAW): h2 writes complete before wave0 reads.
        asm volatile("s_waitcnt lgkmcnt(0)" ::: "memory");
        __builtin_amdgcn_s_barrier();

        // ---- final: score = h2 . W3 + b3, wave 0, one lane per edge ----
        if (wave == 0) {
            int e = lane;
            float accf = sbias[256];
            const float* h2p = (const float*)(smem + e * 272);
            #pragma unroll
            for (int kk = 0; kk < 16; ++kk) {
                f32x4 h = *(const f32x4*)(h2p + kk * 4);
                f32x4 w = *(const f32x4*)(&sbias[192 + kk * 4]);
                accf += h[0] * w[0] + h[1] * w[1] + h[2] * w[2] + h[3] * w[3];
            }
            if (e0 + e < E) out[e0 + e] = accf;
        }
        // sync8 (RAW): wave0's h2 reads complete before next converts
        // overwrite the s/d regions.
        asm volatile("s_waitcnt lgkmcnt(0)" ::: "memory");
        __builtin_amdgcn_s_barrier();
    }
}

extern "C" void kernel_launch(void* const* d_in, const int* in_sizes, int n_in,
                              void* d_out, int out_size, void* d_ws, size_t ws_size,
                              hipStream_t stream) {
    const float* z  = (const float*)d_in[0];
    const int*   ei = (const int*)  d_in[1];
    const float* W1 = (const float*)d_in[2];
    const float* b1 = (const float*)d_in[3];
    const float* W2 = (const float*)d_in[4];
    const float* b2 = (const float*)d_in[5];
    const float* W3 = (const float*)d_in[6];
    const float* b3 = (const float*)d_in[7];
    float* out = (float*)d_out;

    int E = in_sizes[1] / 2;

    short* stage1 = (short*)d_ws;          // 65536 shorts = 128 KB
    short* stage2 = stage1 + 65536;        // 8192 shorts  = 16 KB

    prep_kernel<<<288, 256, 0, stream>>>(W1, W2, stage1, stage2);

    int ntiles = (E + 63) / 64;
    int nblk = ntiles < 768 ? ntiles : 768;   // 3 persistent blocks per CU
    link_kernel<<<nblk, 256, 0, stream>>>(z, ei, b1, b2, W3, b3, stage1, stage2,
                                          out, E, ntiles);
}

// Round 9
// 468.010 us; speedup vs baseline: 2.0068x; 2.0068x over previous
//
#include <hip/hip_runtime.h>
#include <stdint.h>

// Link predictor: score[e] = MLP([src,dst,src*dst,|src-dst|]) over 500K edges.
// Round 12: r10 kernel with phase A replaced by global_load_lds DMA gather.
// Evidence: r10 VGPR=56 -> compiler sinks gather loads into a serial
// load->wait->convert chain (~14us/block, the dominant cost; all utils <45%).
// r11 (register prefetch) spilled (WRITE_SIZE 2MB->1GB). global_load_lds has
// NO dest VGPRs: nothing to sink or spill; all 128 row-DMAs per block issue
// back-to-back and drain once at __syncthreads (whose vmcnt(0) drain is
// exactly the wait we need -- no raw barriers anywhere).
//  - staging: fp32 rows linear in LDS [0,64K): row*512 + chunk*16, rows 0..63
//    = src rows of the 64 edges, 64..127 = dst rows. Wave-uniform base rule:
//    wave w instr i -> lds (w*16+i)*1024 + lane*16; per-lane global src
//    row = 32w + 2i + (lane>>5), chunk = lane&31.  [m104/m97 semantics]
//  - convert: read 16 f32x4/thread from staging -> regs -> sync -> write bf16
//    swizzled tiles at [0,32K) (overlay safe after the sync). Same layout as
//    r10, so GEMM1a..final are byte-identical to r10 (proven passing).
//  - LDS 64KB -> 2 blocks/CU; __launch_bounds__(256,2) (cap ~256, no spill).
//    Occupancy 25% accepted: per-block gather collapses 14us -> ~1-3us.
// Keeps: derive-once GEMM1 split (r7), zero-conflict derive (r8).
// d_ws: stage1 = W1 bf16 B-frag layout (65536 shorts), stage2 = W2 (8192 shorts).

typedef __bf16 bf16x8 __attribute__((ext_vector_type(8)));
typedef __bf16 bf16x4 __attribute__((ext_vector_type(4)));
typedef float  f32x4  __attribute__((ext_vector_type(4)));

__device__ __forceinline__ short f2bf(float f) {
    union { float f; uint32_t u; } v; v.f = f;
    uint32_t u = v.u;
    uint32_t r = (u + 0x7fffu + ((u >> 16) & 1u)) >> 16;   // RNE
    return (short)r;
}

__device__ __forceinline__ void dma16(const float* gsrc, void* ldst) {
    __builtin_amdgcn_global_load_lds(
        (const __attribute__((address_space(1))) uint32_t*)gsrc,
        (__attribute__((address_space(3))) uint32_t*)ldst,
        16, 0, 0);
}

// ---------------- prep: W1/W2 fp32 -> bf16 B-fragment layout ----------------
// stage1[((ntile*16+kstep)*64+lane)*8+j] = bf16(W1[k*128+n]),
//   k = kstep*32 + (lane>>4)*8 + j, n = ntile*16 + (lane&15).
// kstep 0..3 = s rows of W1, 4..7 = d, 8..11 = it, 12..15 = df.
__global__ void prep_kernel(const float* __restrict__ W1, const float* __restrict__ W2,
                            short* __restrict__ stage1, short* __restrict__ stage2) {
    int idx = blockIdx.x * 256 + threadIdx.x;
    if (idx < 65536) {
        int k = idx >> 7, n = idx & 127;
        float v = W1[idx];
        int ntile = n >> 4, ln = n & 15;
        int kstep = k >> 5, kr = k & 31;
        int lane = (kr >> 3) * 16 + ln;
        int j = kr & 7;
        stage1[(((ntile * 16 + kstep) * 64 + lane) << 3) + j] = f2bf(v);
    } else if (idx < 65536 + 8192) {
        int i2 = idx - 65536;
        int k = i2 >> 6, n = i2 & 63;
        float v = W2[i2];
        int ntile = n >> 4, ln = n & 15;
        int kstep = k >> 5, kr = k & 31;
        int lane = (kr >> 3) * 16 + ln;
        int j = kr & 7;
        stage2[(((ntile * 4 + kstep) * 64 + lane) << 3) + j] = f2bf(v);
    }
}

// ---------------- main ----------------
// 64 edges/block, 256 threads (4 waves), 64KB LDS.
// Staging fp32 [0,65536): row*512 + chunk*16 (rows 0..63 s, 64..127 d).
// After convert: s-tile [64 x 128]bf16 at 0 (stride 256B), d-tile at 16384.
//   16B chunk cc = k>>3 stored at physical chunk cc ^ (m&15) (XOR swizzle).
// After GEMM1a: s-tile overwritten in place with it, d-tile with df.
// After GEMM1b: [0,16384) reused for h1 bf16 [64x128] (same swizzle).
// After GEMM2: [0,17408) holds h2 fp32 [64 x 68] (stride 272B).
__launch_bounds__(256, 2)
__global__ void link_kernel(const float* __restrict__ z,
                            const int*   __restrict__ ei,
                            const float* __restrict__ b1,
                            const float* __restrict__ b2,
                            const float* __restrict__ w3,
                            const float* __restrict__ b3,
                            const short* __restrict__ stage1,
                            const short* __restrict__ stage2,
                            float* __restrict__ out,
                            int E) {
    __shared__ __align__(16) char smem[65536];

    const int tid  = threadIdx.x;
    const int lane = tid & 63;
    const int wave = tid >> 6;
    const int ln15 = lane & 15;
    const int quad = lane >> 4;
    const int e0   = blockIdx.x * 64;

    // ---- Phase A1: DMA gather, 128 rows fp32 -> LDS staging (linear) ----
    // wave w, instr i covers staging bytes [(w*16+i)*1024, +1024):
    //   row = 32w + 2i + (lane>>5), chunk = lane&31.
    {
        const int hi  = lane >> 5;          // 0/1
        const int ch  = lane & 31;
        const int arr = wave >> 1;          // 0: src rows, 1: dst rows
        const int rb  = (wave & 1) * 32;    // row base within the 64-edge tile
        int idxs[16];
        #pragma unroll
        for (int i = 0; i < 16; ++i) {
            int e  = rb + 2 * i + hi;       // 0..63
            int eg = e0 + e;
            int egc = eg < E ? eg : (E - 1);
            idxs[i] = ei[arr * E + egc];
        }
        #pragma unroll
        for (int i = 0; i < 16; ++i) {
            const float* src = z + (size_t)idxs[i] * 128 + ch * 4;
            void* dst = smem + (size_t)((wave * 16 + i) * 1024) + lane * 16;
            dma16(src, dst);
        }
    }
    __syncthreads();   // drains DMA (vmcnt(0)) + publishes staging

    // ---- Phase A2: convert staging fp32 -> regs -> bf16 tiles (swizzled) ----
    const int c    = tid & 31;
    const int mrow = tid >> 5;
    const int cc   = c >> 1;
    const int half = c & 1;
    f32x4 sv[8], dv[8];
    #pragma unroll
    for (int i = 0; i < 8; ++i) {
        int m = mrow + i * 8;
        sv[i] = *(const f32x4*)(smem + m * 512 + c * 16);
        dv[i] = *(const f32x4*)(smem + 32768 + m * 512 + c * 16);
    }
    __syncthreads();   // all staging reads done before overlay writes

    #pragma unroll
    for (int i = 0; i < 8; ++i) {
        int m = mrow + i * 8;
        int addr = m * 256 + ((cc ^ (m & 15)) << 4) + half * 8;
        bf16x4 ps, pd;
        #pragma unroll
        for (int j = 0; j < 4; ++j) { ps[j] = (__bf16)sv[i][j]; pd[j] = (__bf16)dv[i][j]; }
        *(bf16x4*)(smem + addr)         = ps;
        *(bf16x4*)(smem + 16384 + addr) = pd;
    }
    __syncthreads();

    // ---- GEMM1a: acc += s@W1s + d@W1d. Wave owns n-tiles wave*2, wave*2+1. ----
    f32x4 acc[4][2];
    #pragma unroll
    for (int mt = 0; mt < 4; ++mt)
        #pragma unroll
        for (int nt = 0; nt < 2; ++nt)
            acc[mt][nt] = (f32x4){0.f, 0.f, 0.f, 0.f};

    #pragma unroll
    for (int ks4 = 0; ks4 < 4; ++ks4) {
        bf16x8 Bs[2], Bd[2];
        #pragma unroll
        for (int nt = 0; nt < 2; ++nt) {
            int ntile = wave * 2 + nt;
            Bs[nt] = *(const bf16x8*)(stage1 + (((ntile * 16 + 0 + ks4) * 64 + lane) << 3));
            Bd[nt] = *(const bf16x8*)(stage1 + (((ntile * 16 + 4 + ks4) * 64 + lane) << 3));
        }
        #pragma unroll
        for (int mt = 0; mt < 4; ++mt) {
            int m = mt * 16 + ln15;
            int off = m * 256 + (((ks4 * 4 + quad) ^ (m & 15)) << 4);
            bf16x8 sf = *(const bf16x8*)(smem + off);
            bf16x8 df = *(const bf16x8*)(smem + 16384 + off);
            #pragma unroll
            for (int nt = 0; nt < 2; ++nt) {
                acc[mt][nt] = __builtin_amdgcn_mfma_f32_16x16x32_bf16(sf, Bs[nt], acc[mt][nt], 0, 0, 0);
                acc[mt][nt] = __builtin_amdgcn_mfma_f32_16x16x32_bf16(df, Bd[nt], acc[mt][nt], 0, 0, 0);
            }
        }
    }
    __syncthreads();   // all waves done reading s,d

    // ---- derive ONCE: it -> s-region, df -> d-region (zero-conflict) ----
    {
        int mder = wave * 16 + ln15;    // mder & 15 == ln15
        #pragma unroll
        for (int ks4 = 0; ks4 < 4; ++ks4) {
            int addr = mder * 256 + (((ks4 * 4 + quad) ^ ln15) << 4);
            bf16x8 s = *(const bf16x8*)(smem + addr);
            bf16x8 d = *(const bf16x8*)(smem + 16384 + addr);
            bf16x8 it, dd;
            #pragma unroll
            for (int j = 0; j < 8; ++j) {
                float fs = (float)s[j], fd = (float)d[j];
                it[j] = (__bf16)(fs * fd);
                dd[j] = (__bf16)__builtin_fabsf(fs - fd);
            }
            *(bf16x8*)(smem + addr)         = it;
            *(bf16x8*)(smem + 16384 + addr) = dd;
        }
    }
    __syncthreads();

    // ---- GEMM1b: acc += it@W1it + df@W1df ----
    #pragma unroll
    for (int ks4 = 0; ks4 < 4; ++ks4) {
        bf16x8 Bi[2], Bf[2];
        #pragma unroll
        for (int nt = 0; nt < 2; ++nt) {
            int ntile = wave * 2 + nt;
            Bi[nt] = *(const bf16x8*)(stage1 + (((ntile * 16 +  8 + ks4) * 64 + lane) << 3));
            Bf[nt] = *(const bf16x8*)(stage1 + (((ntile * 16 + 12 + ks4) * 64 + lane) << 3));
        }
        #pragma unroll
        for (int mt = 0; mt < 4; ++mt) {
            int m = mt * 16 + ln15;
            int off = m * 256 + (((ks4 * 4 + quad) ^ (m & 15)) << 4);
            bf16x8 itf = *(const bf16x8*)(smem + off);
            bf16x8 ddf = *(const bf16x8*)(smem + 16384 + off);
            #pragma unroll
            for (int nt = 0; nt < 2; ++nt) {
                acc[mt][nt] = __builtin_amdgcn_mfma_f32_16x16x32_bf16(itf, Bi[nt], acc[mt][nt], 0, 0, 0);
                acc[mt][nt] = __builtin_amdgcn_mfma_f32_16x16x32_bf16(ddf, Bf[nt], acc[mt][nt], 0, 0, 0);
            }
        }
    }
    __syncthreads();   // all waves done reading it,df

    // ---- epilogue 1: h1 = relu(acc + b1) -> LDS bf16 [64 x 128] at 0, swizzled ----
    #pragma unroll
    for (int nt = 0; nt < 2; ++nt) {
        int n = (wave * 2 + nt) * 16 + ln15;      // = k2 for GEMM2
        float bias = b1[n];
        #pragma unroll
        for (int mt = 0; mt < 4; ++mt) {
            #pragma unroll
            for (int r = 0; r < 4; ++r) {
                int row = mt * 16 + quad * 4 + r;  // C/D: row = quad*4 + reg
                float h = acc[mt][nt][r] + bias;
                h = h > 0.f ? h : 0.f;
                int addr = row * 256 + (((n >> 3) ^ (row & 15)) << 4) + (n & 7) * 2;
                *(short*)(smem + addr) = f2bf(h);
            }
        }
    }
    __syncthreads();

    // ---- GEMM2: h1[64x128] @ W2[128x64]; wave w owns n-tile w (16 cols) ----
    f32x4 acc2[4];
    #pragma unroll
    for (int mt = 0; mt < 4; ++mt) acc2[mt] = (f32x4){0.f, 0.f, 0.f, 0.f};

    #pragma unroll
    for (int ks = 0; ks < 4; ++ks) {
        bf16x8 b = *(const bf16x8*)(stage2 + (((wave * 4 + ks) * 64 + lane) << 3));
        #pragma unroll
        for (int mt = 0; mt < 4; ++mt) {
            int m = mt * 16 + ln15;
            int ccr = ks * 4 + quad;
            bf16x8 a = *(const bf16x8*)(smem + m * 256 + ((ccr ^ (m & 15)) << 4));
            acc2[mt] = __builtin_amdgcn_mfma_f32_16x16x32_bf16(a, b, acc2[mt], 0, 0, 0);
        }
    }
    __syncthreads();   // all waves done reading h1

    // ---- epilogue 2: h2 = relu(acc2 + b2) -> LDS fp32 [64 x 68] at 0 ----
    {
        int n2 = wave * 16 + ln15;
        float bias = b2[n2];
        #pragma unroll
        for (int mt = 0; mt < 4; ++mt) {
            #pragma unroll
            for (int r = 0; r < 4; ++r) {
                int row = mt * 16 + quad * 4 + r;
                float h = acc2[mt][r] + bias;
                h = h > 0.f ? h : 0.f;
                *(float*)(smem + row * 272 + n2 * 4) = h;
            }
        }
    }
    __syncthreads();

    // ---- final: score = h2 . W3 + b3 (fp32), wave 0, one lane per edge ----
    if (wave == 0) {
        int e = lane;
        float accf = b3[0];
        const float* h2p = (const float*)(smem + e * 272);
        #pragma unroll
        for (int kk = 0; kk < 16; ++kk) {
            f32x4 h = *(const f32x4*)(h2p + kk * 4);
            f32x4 w = *(const f32x4*)(w3 + kk * 4);
            accf += h[0] * w[0] + h[1] * w[1] + h[2] * w[2] + h[3] * w[3];
        }
        if (e0 + e < E) out[e0 + e] = accf;
    }
}

extern "C" void kernel_launch(void* const* d_in, const int* in_sizes, int n_in,
                              void* d_out, int out_size, void* d_ws, size_t ws_size,
                              hipStream_t stream) {
    const float* z  = (const float*)d_in[0];
    const int*   ei = (const int*)  d_in[1];
    const float* W1 = (const float*)d_in[2];
    const float* b1 = (const float*)d_in[3];
    const float* W2 = (const float*)d_in[4];
    const float* b2 = (const float*)d_in[5];
    const float* W3 = (const float*)d_in[6];
    const float* b3 = (const float*)d_in[7];
    float* out = (float*)d_out;

    int E = in_sizes[1] / 2;

    short* stage1 = (short*)d_ws;          // 65536 shorts = 128 KB
    short* stage2 = stage1 + 65536;        // 8192 shorts  = 16 KB

    prep_kernel<<<288, 256, 0, stream>>>(W1, W2, stage1, stage2);

    int nblk = (E + 63) / 64;
    link_kernel<<<nblk, 256, 0, stream>>>(z, ei, b1, b2, W3, b3, stage1, stage2, out, E);
}

// Round 10
// 427.102 us; speedup vs baseline: 2.1991x; 1.0958x over previous
//
#include <hip/hip_runtime.h>
#include <stdint.h>

// Link predictor: score[e] = MLP([src,dst,src*dst,|src-dst|]) over 500K edges.
// Round 13: DMA gather (r12, per-block 20.8->14.1us proven) at 32KB LDS
// (r10's 4 blocks/CU, occ ~41% proven). r12's only regression was LDS 64KB ->
// 2 blocks/CU (occ 21%), which cost more than the DMA saved.
//  - staging: ONE 32KB buffer, TWO DMA rounds. Round 1: 64 src rows fp32 ->
//    [0,32K), sync, pull sv[8] to regs, sync. Round 2: same for dst -> dv[8].
//    Then write swizzled bf16 tiles over the staging region, sync.
//  - addressing per round: wave w instr i -> lds w*8192 + i*1024 + lane*16;
//    global row = 16w + 2i + (lane>>5), chunk = lane&31 (r12-verified form).
//  - __syncthreads drains vmcnt(0) (m97) = exactly the DMA wait needed.
//  - two serial HBM drains/block, both overlapped by 3 co-resident blocks.
//  - GEMM1a..final byte-identical to r10/r12 (passing). VGPR est ~90-110
//    under (256,4) cap 128 (r12 measured 88 with heavier pattern).
// Keeps: derive-once GEMM1 split (r7), zero-conflict derive (r8).
// d_ws: stage1 = W1 bf16 B-frag layout (65536 shorts), stage2 = W2 (8192 shorts).

typedef __bf16 bf16x8 __attribute__((ext_vector_type(8)));
typedef __bf16 bf16x4 __attribute__((ext_vector_type(4)));
typedef float  f32x4  __attribute__((ext_vector_type(4)));

__device__ __forceinline__ short f2bf(float f) {
    union { float f; uint32_t u; } v; v.f = f;
    uint32_t u = v.u;
    uint32_t r = (u + 0x7fffu + ((u >> 16) & 1u)) >> 16;   // RNE
    return (short)r;
}

__device__ __forceinline__ void dma16(const float* gsrc, void* ldst) {
    __builtin_amdgcn_global_load_lds(
        (const __attribute__((address_space(1))) uint32_t*)gsrc,
        (__attribute__((address_space(3))) uint32_t*)ldst,
        16, 0, 0);
}

// ---------------- prep: W1/W2 fp32 -> bf16 B-fragment layout ----------------
// stage1[((ntile*16+kstep)*64+lane)*8+j] = bf16(W1[k*128+n]),
//   k = kstep*32 + (lane>>4)*8 + j, n = ntile*16 + (lane&15).
// kstep 0..3 = s rows of W1, 4..7 = d, 8..11 = it, 12..15 = df.
__global__ void prep_kernel(const float* __restrict__ W1, const float* __restrict__ W2,
                            short* __restrict__ stage1, short* __restrict__ stage2) {
    int idx = blockIdx.x * 256 + threadIdx.x;
    if (idx < 65536) {
        int k = idx >> 7, n = idx & 127;
        float v = W1[idx];
        int ntile = n >> 4, ln = n & 15;
        int kstep = k >> 5, kr = k & 31;
        int lane = (kr >> 3) * 16 + ln;
        int j = kr & 7;
        stage1[(((ntile * 16 + kstep) * 64 + lane) << 3) + j] = f2bf(v);
    } else if (idx < 65536 + 8192) {
        int i2 = idx - 65536;
        int k = i2 >> 6, n = i2 & 63;
        float v = W2[i2];
        int ntile = n >> 4, ln = n & 15;
        int kstep = k >> 5, kr = k & 31;
        int lane = (kr >> 3) * 16 + ln;
        int j = kr & 7;
        stage2[(((ntile * 4 + kstep) * 64 + lane) << 3) + j] = f2bf(v);
    }
}

// ---------------- main ----------------
// 64 edges/block, 256 threads (4 waves), 32KB LDS.
// Staging fp32 [0,32768): row*512 + chunk*16, 64 rows (src round, then dst).
// After convert: s-tile [64 x 128]bf16 at 0 (stride 256B), d-tile at 16384.
//   16B chunk cc = k>>3 stored at physical chunk cc ^ (m&15) (XOR swizzle).
// After GEMM1a: s-tile overwritten in place with it, d-tile with df.
// After GEMM1b: [0,16384) reused for h1 bf16 [64x128] (same swizzle).
// After GEMM2: [0,17408) holds h2 fp32 [64 x 68] (stride 272B).
__launch_bounds__(256, 4)
__global__ void link_kernel(const float* __restrict__ z,
                            const int*   __restrict__ ei,
                            const float* __restrict__ b1,
                            const float* __restrict__ b2,
                            const float* __restrict__ w3,
                            const float* __restrict__ b3,
                            const short* __restrict__ stage1,
                            const short* __restrict__ stage2,
                            float* __restrict__ out,
                            int E) {
    __shared__ __align__(16) char smem[32768];

    const int tid  = threadIdx.x;
    const int lane = tid & 63;
    const int wave = tid >> 6;
    const int ln15 = lane & 15;
    const int quad = lane >> 4;
    const int e0   = blockIdx.x * 64;

    const int c    = tid & 31;
    const int mrow = tid >> 5;
    const int cc   = c >> 1;
    const int half = c & 1;
    const int hi   = lane >> 5;          // 0/1
    const int ch   = lane & 31;

    f32x4 sv[8], dv[8];

    // ---- Phase A, round 1: DMA 64 src rows fp32 -> staging [0,32K) ----
    // wave w, instr i -> staging bytes [w*8192 + i*1024, +1024):
    //   row = 16w + 2i + hi, chunk = ch.
    {
        int idxs[8];
        #pragma unroll
        for (int i = 0; i < 8; ++i) {
            int eg  = e0 + wave * 16 + 2 * i + hi;
            int egc = eg < E ? eg : (E - 1);
            idxs[i] = ei[egc];
        }
        #pragma unroll
        for (int i = 0; i < 8; ++i) {
            const float* src = z + (size_t)idxs[i] * 128 + ch * 4;
            void* dst = smem + (wave * 8192 + i * 1024) + lane * 16;
            dma16(src, dst);
        }
    }
    __syncthreads();   // drain src DMA (vmcnt(0))
    #pragma unroll
    for (int i = 0; i < 8; ++i) {
        int m = mrow + i * 8;
        sv[i] = *(const f32x4*)(smem + m * 512 + c * 16);
    }
    __syncthreads();   // all staging reads done

    // ---- Phase A, round 2: DMA 64 dst rows fp32 -> staging [0,32K) ----
    {
        int idxs[8];
        #pragma unroll
        for (int i = 0; i < 8; ++i) {
            int eg  = e0 + wave * 16 + 2 * i + hi;
            int egc = eg < E ? eg : (E - 1);
            idxs[i] = ei[E + egc];
        }
        #pragma unroll
        for (int i = 0; i < 8; ++i) {
            const float* src = z + (size_t)idxs[i] * 128 + ch * 4;
            void* dst = smem + (wave * 8192 + i * 1024) + lane * 16;
            dma16(src, dst);
        }
    }
    __syncthreads();   // drain dst DMA
    #pragma unroll
    for (int i = 0; i < 8; ++i) {
        int m = mrow + i * 8;
        dv[i] = *(const f32x4*)(smem + m * 512 + c * 16);
    }
    __syncthreads();   // all staging reads done

    // ---- convert: sv/dv regs -> bf16 tiles (swizzled), overlay staging ----
    #pragma unroll
    for (int i = 0; i < 8; ++i) {
        int m = mrow + i * 8;
        int addr = m * 256 + ((cc ^ (m & 15)) << 4) + half * 8;
        bf16x4 ps, pd;
        #pragma unroll
        for (int j = 0; j < 4; ++j) { ps[j] = (__bf16)sv[i][j]; pd[j] = (__bf16)dv[i][j]; }
        *(bf16x4*)(smem + addr)         = ps;
        *(bf16x4*)(smem + 16384 + addr) = pd;
    }
    __syncthreads();

    // ---- GEMM1a: acc += s@W1s + d@W1d. Wave owns n-tiles wave*2, wave*2+1. ----
    f32x4 acc[4][2];
    #pragma unroll
    for (int mt = 0; mt < 4; ++mt)
        #pragma unroll
        for (int nt = 0; nt < 2; ++nt)
            acc[mt][nt] = (f32x4){0.f, 0.f, 0.f, 0.f};

    #pragma unroll
    for (int ks4 = 0; ks4 < 4; ++ks4) {
        bf16x8 Bs[2], Bd[2];
        #pragma unroll
        for (int nt = 0; nt < 2; ++nt) {
            int ntile = wave * 2 + nt;
            Bs[nt] = *(const bf16x8*)(stage1 + (((ntile * 16 + 0 + ks4) * 64 + lane) << 3));
            Bd[nt] = *(const bf16x8*)(stage1 + (((ntile * 16 + 4 + ks4) * 64 + lane) << 3));
        }
        #pragma unroll
        for (int mt = 0; mt < 4; ++mt) {
            int m = mt * 16 + ln15;
            int off = m * 256 + (((ks4 * 4 + quad) ^ (m & 15)) << 4);
            bf16x8 sf = *(const bf16x8*)(smem + off);
            bf16x8 df = *(const bf16x8*)(smem + 16384 + off);
            #pragma unroll
            for (int nt = 0; nt < 2; ++nt) {
                acc[mt][nt] = __builtin_amdgcn_mfma_f32_16x16x32_bf16(sf, Bs[nt], acc[mt][nt], 0, 0, 0);
                acc[mt][nt] = __builtin_amdgcn_mfma_f32_16x16x32_bf16(df, Bd[nt], acc[mt][nt], 0, 0, 0);
            }
        }
    }
    __syncthreads();   // all waves done reading s,d

    // ---- derive ONCE: it -> s-region, df -> d-region (zero-conflict) ----
    {
        int mder = wave * 16 + ln15;    // mder & 15 == ln15
        #pragma unroll
        for (int ks4 = 0; ks4 < 4; ++ks4) {
            int addr = mder * 256 + (((ks4 * 4 + quad) ^ ln15) << 4);
            bf16x8 s = *(const bf16x8*)(smem + addr);
            bf16x8 d = *(const bf16x8*)(smem + 16384 + addr);
            bf16x8 it, dd;
            #pragma unroll
            for (int j = 0; j < 8; ++j) {
                float fs = (float)s[j], fd = (float)d[j];
                it[j] = (__bf16)(fs * fd);
                dd[j] = (__bf16)__builtin_fabsf(fs - fd);
            }
            *(bf16x8*)(smem + addr)         = it;
            *(bf16x8*)(smem + 16384 + addr) = dd;
        }
    }
    __syncthreads();

    // ---- GEMM1b: acc += it@W1it + df@W1df ----
    #pragma unroll
    for (int ks4 = 0; ks4 < 4; ++ks4) {
        bf16x8 Bi[2], Bf[2];
        #pragma unroll
        for (int nt = 0; nt < 2; ++nt) {
            int ntile = wave * 2 + nt;
            Bi[nt] = *(const bf16x8*)(stage1 + (((ntile * 16 +  8 + ks4) * 64 + lane) << 3));
            Bf[nt] = *(const bf16x8*)(stage1 + (((ntile * 16 + 12 + ks4) * 64 + lane) << 3));
        }
        #pragma unroll
        for (int mt = 0; mt < 4; ++mt) {
            int m = mt * 16 + ln15;
            int off = m * 256 + (((ks4 * 4 + quad) ^ (m & 15)) << 4);
            bf16x8 itf = *(const bf16x8*)(smem + off);
            bf16x8 ddf = *(const bf16x8*)(smem + 16384 + off);
            #pragma unroll
            for (int nt = 0; nt < 2; ++nt) {
                acc[mt][nt] = __builtin_amdgcn_mfma_f32_16x16x32_bf16(itf, Bi[nt], acc[mt][nt], 0, 0, 0);
                acc[mt][nt] = __builtin_amdgcn_mfma_f32_16x16x32_bf16(ddf, Bf[nt], acc[mt][nt], 0, 0, 0);
            }
        }
    }
    __syncthreads();   // all waves done reading it,df

    // ---- epilogue 1: h1 = relu(acc + b1) -> LDS bf16 [64 x 128] at 0, swizzled ----
    #pragma unroll
    for (int nt = 0; nt < 2; ++nt) {
        int n = (wave * 2 + nt) * 16 + ln15;      // = k2 for GEMM2
        float bias = b1[n];
        #pragma unroll
        for (int mt = 0; mt < 4; ++mt) {
            #pragma unroll
            for (int r = 0; r < 4; ++r) {
                int row = mt * 16 + quad * 4 + r;  // C/D: row = quad*4 + reg
                float h = acc[mt][nt][r] + bias;
                h = h > 0.f ? h : 0.f;
                int addr = row * 256 + (((n >> 3) ^ (row & 15)) << 4) + (n & 7) * 2;
                *(short*)(smem + addr) = f2bf(h);
            }
        }
    }
    __syncthreads();

    // ---- GEMM2: h1[64x128] @ W2[128x64]; wave w owns n-tile w (16 cols) ----
    f32x4 acc2[4];
    #pragma unroll
    for (int mt = 0; mt < 4; ++mt) acc2[mt] = (f32x4){0.f, 0.f, 0.f, 0.f};

    #pragma unroll
    for (int ks = 0; ks < 4; ++ks) {
        bf16x8 b = *(const bf16x8*)(stage2 + (((wave * 4 + ks) * 64 + lane) << 3));
        #pragma unroll
        for (int mt = 0; mt < 4; ++mt) {
            int m = mt * 16 + ln15;
            int ccr = ks * 4 + quad;
            bf16x8 a = *(const bf16x8*)(smem + m * 256 + ((ccr ^ (m & 15)) << 4));
            acc2[mt] = __builtin_amdgcn_mfma_f32_16x16x32_bf16(a, b, acc2[mt], 0, 0, 0);
        }
    }
    __syncthreads();   // all waves done reading h1

    // ---- epilogue 2: h2 = relu(acc2 + b2) -> LDS fp32 [64 x 68] at 0 ----
    {
        int n2 = wave * 16 + ln15;
        float bias = b2[n2];
        #pragma unroll
        for (int mt = 0; mt < 4; ++mt) {
            #pragma unroll
            for (int r = 0; r < 4; ++r) {
                int row = mt * 16 + quad * 4 + r;
                float h = acc2[mt][r] + bias;
                h = h > 0.f ? h : 0.f;
                *(float*)(smem + row * 272 + n2 * 4) = h;
            }
        }
    }
    __syncthreads();

    // ---- final: score = h2 . W3 + b3 (fp32), wave 0, one lane per edge ----
    if (wave == 0) {
        int e = lane;
        float accf = b3[0];
        const float* h2p = (const float*)(smem + e * 272);
        #pragma unroll
        for (int kk = 0; kk < 16; ++kk) {
            f32x4 h = *(const f32x4*)(h2p + kk * 4);
            f32x4 w = *(const f32x4*)(w3 + kk * 4);
            accf += h[0] * w[0] + h[1] * w[1] + h[2] * w[2] + h[3] * w[3];
        }
        if (e0 + e < E) out[e0 + e] = accf;
    }
}

extern "C" void kernel_launch(void* const* d_in, const int* in_sizes, int n_in,
                              void* d_out, int out_size, void* d_ws, size_t ws_size,
                              hipStream_t stream) {
    const float* z  = (const float*)d_in[0];
    const int*   ei = (const int*)  d_in[1];
    const float* W1 = (const float*)d_in[2];
    const float* b1 = (const float*)d_in[3];
    const float* W2 = (const float*)d_in[4];
    const float* b2 = (const float*)d_in[5];
    const float* W3 = (const float*)d_in[6];
    const float* b3 = (const float*)d_in[7];
    float* out = (float*)d_out;

    int E = in_sizes[1] / 2;

    short* stage1 = (short*)d_ws;          // 65536 shorts = 128 KB
    short* stage2 = stage1 + 65536;        // 8192 shorts  = 16 KB

    prep_kernel<<<288, 256, 0, stream>>>(W1, W2, stage1, stage2);

    int nblk = (E + 63) / 64;
    link_kernel<<<nblk, 256, 0, stream>>>(z, ei, b1, b2, W3, b3, stage1, stage2, out, E);
}